// Round 2
// baseline (617.875 us; speedup 1.0000x reference)
//
#include <hip/hip_runtime.h>
#include <hip/hip_bf16.h>
#include <stdint.h>

using bf16 = __hip_bfloat16;
typedef short bf16x8 __attribute__((ext_vector_type(8)));
typedef float floatx4 __attribute__((ext_vector_type(4)));

static constexpr int NODES = 2048;
static constexpr int EDGES = 32768;

// pack 8 consecutive f32 -> 8 bf16 (rne) as uint4
__device__ inline uint4 cvt8(const float* __restrict__ p) {
    const float4* f = (const float4*)p;
    float4 a = f[0], b = f[1];
    union { uint4 u; bf16 h[8]; } pk;
    pk.h[0] = __float2bfloat16(a.x); pk.h[1] = __float2bfloat16(a.y);
    pk.h[2] = __float2bfloat16(a.z); pk.h[3] = __float2bfloat16(a.w);
    pk.h[4] = __float2bfloat16(b.x); pk.h[5] = __float2bfloat16(b.y);
    pk.h[6] = __float2bfloat16(b.z); pk.h[7] = __float2bfloat16(b.w);
    return pk.u;
}

// ---------------- generic BMxBN MFMA GEMM body (bf16 MFMA core) ------------
// C[m,n] = epilogue( sum_k A[m,k] * B'[n,k] + bias[n] )
// AMODE 0: A bf16 scratch [M,K]
// AMODE 1: A f32 [M,K] (cvt in staging)
// AMODE 3: A row e = relu(U[sidx[e]][k] + V[ridx[e]][k] + b1[k]), U/V bf16 (K=512)
// BMODE 0: B' = Bt f32 [N,K]
// BMODE 1: B' row n = msg_W1[n&511][ (n>>9)*256 .. +K ]  (split W1 halves)
// BMODE 2: B' = Bt already bf16 [N,K] (pre-converted weights, no cvt)
// EPI 0: +bias, relu, store bf16 Cout[M,N]
// EPI 2: +bias, add f32 residual inputsF[m,n], store f32 OutF (N==256)
// EPI 4: raw bf16 store Cout[M,N] (no bias)
// EPI 5: +bias, relu, store f32 OutF[M,N]  (edge msg output, no atomics)
template<int BM, int BN, int AMODE, int BMODE, int EPI>
__device__ __forceinline__ void gemm_body(
    const bf16* __restrict__ A, const float* __restrict__ Af,
    const float* __restrict__ Bt, const float* __restrict__ bias,
    bf16* __restrict__ Cout, float* __restrict__ OutF,
    const float* __restrict__ inputsF, const bf16* __restrict__ UVb,
    const float* __restrict__ b1v, const int* __restrict__ sidx,
    const int* __restrict__ ridx, int M, int N, int K, int bx, int by)
{
    constexpr int BK = 32;
    constexpr int PA = BM / 64;   // A staging passes (16B/thread each)
    constexpr int PB = BN / 64;
    constexpr int MI = BM / 32;   // per-wave 16-tiles in M
    constexpr int NJ = BN / 32;   // per-wave 16-tiles in N
    __shared__ bf16 As[BM * BK];
    __shared__ bf16 Bs[BN * BK];
    __shared__ int sIdx[BM];
    __shared__ int rIdx[BM];

    const int t = threadIdx.x;
    const int m0 = by * BM;
    const int n0 = bx * BN;

    if constexpr (AMODE == 3) {
        if (t < BM) {
            sIdx[t] = sidx[m0 + t] & (NODES - 1);   // OOB structurally impossible
            rIdx[t] = ridx[m0 + t] & (NODES - 1);
        }
        __syncthreads();
    }

    // staging: thread t covers LDS row (p*64 + t/4), 16B bf16 chunk (t%4)
    const int sr = t >> 2;
    const int sc = t & 3;

    uint4 ra[PA], rb[PB];

    auto loadTiles = [&](int kt) {
        const int kk = kt * BK + sc * 8;   // element column within K
#pragma unroll
        for (int p = 0; p < PA; ++p) {
            const int row = p * 64 + sr;
            if constexpr (AMODE == 0) {
                ra[p] = *(const uint4*)(A + (size_t)(m0 + row) * K + kk);
            } else if constexpr (AMODE == 1) {
                ra[p] = cvt8(Af + (size_t)(m0 + row) * K + kk);
            } else {
                union { uint4 q; unsigned short h[8]; } uu, vv;
                uu.q = *(const uint4*)(UVb + (size_t)sIdx[row] * 1024 + kk);
                vv.q = *(const uint4*)(UVb + (size_t)rIdx[row] * 1024 + 512 + kk);
                const float4* c = (const float4*)(b1v + kk);
                float4 c0 = c[0], c1 = c[1];
                const float cf[8] = {c0.x, c0.y, c0.z, c0.w, c1.x, c1.y, c1.z, c1.w};
                union { uint4 q; bf16 h[8]; } pk;
#pragma unroll
                for (int e = 0; e < 8; ++e) {
                    union { unsigned int u; float f; } a2, b2;
                    a2.u = (unsigned int)uu.h[e] << 16;
                    b2.u = (unsigned int)vv.h[e] << 16;
                    pk.h[e] = __float2bfloat16(fmaxf(a2.f + b2.f + cf[e], 0.f));
                }
                ra[p] = pk.q;
            }
        }
#pragma unroll
        for (int p = 0; p < PB; ++p) {
            const int row = p * 64 + sr;
            if constexpr (BMODE == 0) {
                rb[p] = cvt8(Bt + (size_t)(n0 + row) * K + kk);
            } else if constexpr (BMODE == 2) {
                rb[p] = *(const uint4*)(((const bf16*)Bt) + (size_t)(n0 + row) * K + kk);
            } else {
                const int n = n0 + row;
                rb[p] = cvt8(Bt + (size_t)(n & 511) * 512 + (n >> 9) * 256 + kk);
            }
        }
    };

    const int wv = t >> 6;
    const int lane = t & 63;
    const int wm = wv >> 1, wn = wv & 1;   // wave covers (BM/2)x(BN/2)
    const int r16 = lane & 15, q = lane >> 4;

    floatx4 acc[MI][NJ] = {};

    loadTiles(0);
    const int KT = K / BK;
    for (int kt = 0; kt < KT; ++kt) {
        __syncthreads();
#pragma unroll
        for (int p = 0; p < PA; ++p)
            *(uint4*)(&As[(p * 64 + sr) * BK + sc * 8]) = ra[p];
#pragma unroll
        for (int p = 0; p < PB; ++p)
            *(uint4*)(&Bs[(p * 64 + sr) * BK + sc * 8]) = rb[p];
        __syncthreads();
        if (kt + 1 < KT) loadTiles(kt + 1);   // overlap next-tile loads with MFMA

        bf16x8 af[MI], bfr[NJ];
#pragma unroll
        for (int i = 0; i < MI; ++i)
            af[i] = *(const bf16x8*)(&As[(wm * (BM / 2) + i * 16 + r16) * BK + q * 8]);
#pragma unroll
        for (int j = 0; j < NJ; ++j)
            bfr[j] = *(const bf16x8*)(&Bs[(wn * (BN / 2) + j * 16 + r16) * BK + q * 8]);
#pragma unroll
        for (int i = 0; i < MI; ++i)
#pragma unroll
            for (int j = 0; j < NJ; ++j)
                acc[i][j] = __builtin_amdgcn_mfma_f32_16x16x32_bf16(af[i], bfr[j], acc[i][j], 0, 0, 0);
    }

    float bv[NJ];
#pragma unroll
    for (int j = 0; j < NJ; ++j)
        bv[j] = (EPI == 4) ? 0.f : bias[n0 + wn * (BN / 2) + j * 16 + r16];

    // C/D layout: col = lane&15, row = q*4 + r (verified m89/m91)
#pragma unroll
    for (int i = 0; i < MI; ++i) {
        const int lr = wm * (BM / 2) + i * 16 + q * 4;
        const int rbase = m0 + lr;
#pragma unroll
        for (int j = 0; j < NJ; ++j) {
            const int gc = n0 + wn * (BN / 2) + j * 16 + r16;
#pragma unroll
            for (int r = 0; r < 4; ++r) {
                float v = acc[i][j][r] + bv[j];
                const int gr = rbase + r;
                if constexpr (EPI == 0) {
                    v = fmaxf(v, 0.0f);
                    Cout[(size_t)gr * N + gc] = __float2bfloat16(v);
                } else if constexpr (EPI == 2) {
                    OutF[(size_t)gr * 256 + gc] = inputsF[(size_t)gr * 256 + gc] + v;
                } else if constexpr (EPI == 5) {
                    OutF[(size_t)gr * N + gc] = fmaxf(v, 0.0f);
                } else {
                    Cout[(size_t)gr * N + gc] = __float2bfloat16(v);
                }
            }
        }
    }
}

template<int BM, int BN, int AMODE, int BMODE, int EPI>
__global__ __launch_bounds__(256, 2) void gemm_k(
    const bf16* __restrict__ A, const float* __restrict__ Af,
    const float* __restrict__ Bt, const float* __restrict__ bias,
    bf16* __restrict__ Cout, float* __restrict__ OutF,
    const float* __restrict__ inputsF, const bf16* __restrict__ UVb,
    const float* __restrict__ b1v, const int* __restrict__ sidx,
    const int* __restrict__ ridx, int M, int N, int K)
{
    gemm_body<BM, BN, AMODE, BMODE, EPI>(A, Af, Bt, bias, Cout, OutF, inputsF,
        UVb, b1v, sidx, ridx, M, N, K, blockIdx.x, blockIdx.y);
}

// ---------------- fused node MLP: scatter-gather + 3 layers per 16 rows ----
// Each block owns 16 nodes. Phase 0: scan recv_idx (128 KB, L2-resident),
// build per-node edge lists in LDS; lane-parallel f32-sum the matching msg
// rows straight into the LDS A-tile (no global atomics anywhere). Then 3
// MFMA layers with intermediates in LDS (stride 520 -> max 2-way bank
// aliasing = free). B fragments double-buffered from L2-resident bf16
// weights.
template<int NJ, int EPI>   // EPI 0: relu -> LDS bf16 ; EPI 1: +inputs residual -> f32 global
__device__ __forceinline__ void mlp_layer(
    const bf16* __restrict__ Asrc, const bf16* __restrict__ W,
    const float* __restrict__ bias, bf16* __restrict__ dst,
    const float* __restrict__ inputsF, float* __restrict__ outF,
    int m0, int wv, int r16, int q)
{
    constexpr int LDR = 520;
    const int ncol0 = wv * NJ * 16;
    floatx4 acc[NJ] = {};
    bf16x8 bb0[NJ], bb1[NJ];
    bf16x8 aa0, aa1;

    auto loadB = [&](int kt, bf16x8* d) {
#pragma unroll
        for (int j = 0; j < NJ; ++j)
            d[j] = *(const bf16x8*)(W + (size_t)(ncol0 + j * 16 + r16) * 512 + kt * 32 + q * 8);
    };
    auto loadA = [&](int kt) {
        return *(const bf16x8*)(Asrc + r16 * LDR + kt * 32 + q * 8);
    };

    loadB(0, bb0); aa0 = loadA(0);
#pragma unroll
    for (int kt = 0; kt < 16; kt += 2) {
        loadB(kt + 1, bb1); aa1 = loadA(kt + 1);
#pragma unroll
        for (int j = 0; j < NJ; ++j)
            acc[j] = __builtin_amdgcn_mfma_f32_16x16x32_bf16(aa0, bb0[j], acc[j], 0, 0, 0);
        if (kt + 2 < 16) { loadB(kt + 2, bb0); aa0 = loadA(kt + 2); }
#pragma unroll
        for (int j = 0; j < NJ; ++j)
            acc[j] = __builtin_amdgcn_mfma_f32_16x16x32_bf16(aa1, bb1[j], acc[j], 0, 0, 0);
    }

    // C/D layout: col = lane&15, row = q*4 + r (verified m89/m91)
#pragma unroll
    for (int j = 0; j < NJ; ++j) {
        const int gc = ncol0 + j * 16 + r16;
        const float bvv = bias[gc];
#pragma unroll
        for (int r = 0; r < 4; ++r) {
            float v = acc[j][r] + bvv;
            const int lr = q * 4 + r;
            if constexpr (EPI == 0) {
                dst[lr * LDR + gc] = __float2bfloat16(fmaxf(v, 0.f));
            } else {
                const size_t o = (size_t)(m0 + lr) * 256 + gc;
                outF[o] = inputsF[o] + v;
            }
        }
    }
}

static constexpr int MAXE = 96;   // per-node edge cap (Poisson mean 16; P(>96) ~ 0)

__global__ __launch_bounds__(256, 2) void node_mlp(
    const float* __restrict__ inputs, const float* __restrict__ msg,
    const int* __restrict__ recv_idx,
    const bf16* __restrict__ W1b, const float* __restrict__ b1,
    const bf16* __restrict__ W2b, const float* __restrict__ b2,
    const bf16* __restrict__ W3b, const float* __restrict__ b3,
    float* __restrict__ out)
{
    constexpr int LDR = 520;
    __shared__ bf16 As[16 * LDR];
    __shared__ bf16 Hs[16 * LDR];
    __shared__ bf16 Gs[16 * LDR];
    __shared__ int lcnt[16];
    __shared__ int lst[16 * MAXE];
    const int t = threadIdx.x;
    const int m0 = blockIdx.x * 16;
    if (t < 16) lcnt[t] = 0;

    // stage inputs half (cols 0..255) as bf16 while lcnt settles
#pragma unroll
    for (int p = 0; p < 2; ++p) {
        const int c = t + 256 * p;          // 512 chunks of 8 elems
        const int row = c >> 5;
        const int col = (c & 31) * 8;
        *(uint4*)(&As[row * LDR + col]) = cvt8(inputs + (size_t)(m0 + row) * 256 + col);
    }
    __syncthreads();                        // lcnt zeroed

    // scan recv_idx, collect edges targeting this block's 16 nodes
    for (int i = t; i < EDGES; i += 256) {
        const int r = recv_idx[i];
        if ((r >> 4) == (int)blockIdx.x) {
            const int p = atomicAdd(&lcnt[r & 15], 1);
            if (p < MAXE) lst[(r & 15) * MAXE + p] = i;
        }
    }
    __syncthreads();

    const int wv = t >> 6, lane = t & 63;
    // gather-sum msg rows (f32) -> agg cols 256..511 of As (bf16)
#pragma unroll
    for (int k = 0; k < 4; ++k) {
        const int ln = wv * 4 + k;
        float4 a = {0.f, 0.f, 0.f, 0.f};
        const int cnt = min(lcnt[ln], MAXE);
        for (int e = 0; e < cnt; ++e) {
            const float4 v = *(const float4*)(msg + (size_t)lst[ln * MAXE + e] * 256 + lane * 4);
            a.x += v.x; a.y += v.y; a.z += v.z; a.w += v.w;
        }
        union { ushort4 u; bf16 h[4]; } pk;
        pk.h[0] = __float2bfloat16(a.x); pk.h[1] = __float2bfloat16(a.y);
        pk.h[2] = __float2bfloat16(a.z); pk.h[3] = __float2bfloat16(a.w);
        *(ushort4*)(&As[ln * LDR + 256 + lane * 4]) = pk.u;
    }

    const int r16 = lane & 15, q = lane >> 4;
    __syncthreads();
    mlp_layer<8, 0>(As, W1b, b1, Hs, nullptr, nullptr, m0, wv, r16, q);
    __syncthreads();
    mlp_layer<8, 0>(Hs, W2b, b2, Gs, nullptr, nullptr, m0, wv, r16, q);
    __syncthreads();
    mlp_layer<4, 1>(Gs, W3b, b3, nullptr, inputs, out, m0, wv, r16, q);
}

// ---------------- fat front kernel: UV GEMM + weight cvt + extract ---------
// blocks [0,512):      UV(bf16) = inputs @ [W1_left|W1_right]^T (64x64 tiles)
//                      -- FIRST so they start before the extract flood
// blocks [512,896):    f32->bf16 weight conversion (msg_W2|out_W1|out_W2|out_W3)
// blocks [896,17280):  one-hot index extraction (one wave per row, early exit)
// __launch_bounds__(256,8): cap 64 VGPR so the extract waves keep 8 waves/SIMD
// (extract is HBM-latency-bound, 1 load in flight/wave: occupancy IS bandwidth)
__global__ __launch_bounds__(256, 8) void fat_pre(
    const float* __restrict__ rel_rec, const float* __restrict__ rel_send,
    int* __restrict__ recv_idx, int* __restrict__ send_idx,
    const float* __restrict__ inputs,
    const float* __restrict__ msg_W1, bf16* __restrict__ UVb,
    const float* __restrict__ msg_W2, const float* __restrict__ out_W1,
    const float* __restrict__ out_W2, const float* __restrict__ out_W3,
    bf16* __restrict__ Wc)
{
    const int b = blockIdx.x;
    if (b < 512) {
        gemm_body<64, 64, 1, 1, 4>(nullptr, inputs, msg_W1, nullptr, UVb, nullptr,
            nullptr, nullptr, nullptr, nullptr, nullptr,
            NODES, 1024, 256, b & 15, b >> 4);
    } else if (b < 896) {
        // one-shot weight cvt: gid ranges are block-uniform (boundaries are
        // multiples of 2048), dst is contiguous [msgW2|outW1|outW2|outW3]
        const int gid = (b - 512) * 2048 + threadIdx.x * 8;
        const float* src;
        if (gid < 131072)      src = msg_W2 + gid;
        else if (gid < 393216) src = out_W1 + (gid - 131072);
        else if (gid < 655360) src = out_W2 + (gid - 393216);
        else                   src = out_W3 + (gid - 655360);
        *(uint4*)(Wc + gid) = cvt8(src);
    } else {
        const int eb = b - 896;
        const int half = eb >> 13;         // 0: rel_rec, 1: rel_send
        const int rb = eb & 8191;
        const float* mat = half ? rel_send : rel_rec;
        int* out = half ? send_idx : recv_idx;
        const int w = threadIdx.x >> 6;
        const int lane = threadIdx.x & 63;
        const int row = rb * 4 + w;        // 0..32767
        if (lane == 0) out[row] = 0;       // defensive init
        const uint4* base = (const uint4*)(mat + (size_t)row * NODES);
        for (int p = 0; p < 8; ++p) {
            uint4 v = base[p * 64 + lane];
            const bool hit = (v.x | v.y | v.z | v.w) != 0u;
            if (hit) {
                int e = v.x ? 0 : (v.y ? 1 : (v.z ? 2 : 3));
                out[row] = p * 256 + lane * 4 + e;
            }
            if (__any(hit)) break;         // wave early exit (avg ~4.5/8 passes)
        }
    }
}

extern "C" void kernel_launch(void* const* d_in, const int* in_sizes, int n_in,
                              void* d_out, int out_size, void* d_ws, size_t ws_size,
                              hipStream_t stream) {
    const float* inputs   = (const float*)d_in[0];
    const float* rel_rec  = (const float*)d_in[1];
    const float* rel_send = (const float*)d_in[2];
    const float* msg_W1   = (const float*)d_in[3];
    const float* msg_b1   = (const float*)d_in[4];
    const float* msg_W2   = (const float*)d_in[5];
    const float* msg_b2   = (const float*)d_in[6];
    const float* out_W1   = (const float*)d_in[7];
    const float* out_b1   = (const float*)d_in[8];
    const float* out_W2   = (const float*)d_in[9];
    const float* out_b2   = (const float*)d_in[10];
    const float* out_W3   = (const float*)d_in[11];
    const float* out_b3   = (const float*)d_in[12];

    // workspace layout (~38.3 MB used)
    char* ws = (char*)d_ws;
    int*   recv_idx = (int*)(ws + 0);            // 128 KB
    int*   send_idx = (int*)(ws + 131072);       // 128 KB
    bf16*  UVb      = (bf16*)(ws + 262144);      // 4 MB bf16 [2048,1024] (U|V)
    bf16*  Wc       = (bf16*)(ws + 4456448);     // 1.5 MB bf16 [msgW2|oW1|oW2|oW3]
    float* msg      = (float*)(ws + 6291456);    // 32 MB f32 [32768,256]
    bf16*  W2b  = Wc;                            // 256x512
    bf16*  oW1b = Wc + 131072;                   // 512x512
    bf16*  oW2b = Wc + 393216;                   // 512x512
    bf16*  oW3b = Wc + 655360;                   // 256x512
    if (ws_size < (size_t)40 * 1024 * 1024) return;  // fail loudly, not fault

    // 1) fused: UV GEMM (first!) + weight cvt + index extraction
    fat_pre<<<17280, 256, 0, stream>>>(rel_rec, rel_send, recv_idx, send_idx,
                                       inputs, msg_W1, UVb,
                                       msg_W2, out_W1, out_W2, out_W3, Wc);

    // 2) edge layer-2, 64x256 tile (A gathered/repacked ONCE per row, full N
    //    per block), f32 msg store -- zero global atomics:
    //    msg[e] = relu( relu(U[send[e]]+V[recv[e]]+b1) @ W2b^T + b2 )
    gemm_k<64, 256, 3, 2, 5><<<dim3(1, 512), 256, 0, stream>>>(
        nullptr, nullptr, (const float*)W2b, msg_b2, nullptr, msg,
        nullptr, UVb, msg_b1, send_idx, recv_idx,
        EDGES, 256, 512);

    // 3) fused node MLP: in-block scatter-gather of msg + 3 layers:
    //    out = inputs + mlp3(concat(inputs, sum_{recv[e]=n} msg[e]))
    node_mlp<<<128, 256, 0, stream>>>(
        inputs, msg, recv_idx, oW1b, out_b1, oW2b, out_b2, oW3b, out_b3,
        (float*)d_out);
}

// Round 3
// 584.137 us; speedup vs baseline: 1.0578x; 1.0578x over previous
//
#include <hip/hip_runtime.h>
#include <hip/hip_bf16.h>
#include <stdint.h>

using bf16 = __hip_bfloat16;
typedef short bf16x8 __attribute__((ext_vector_type(8)));
typedef float floatx4 __attribute__((ext_vector_type(4)));

static constexpr int NODES = 2048;
static constexpr int EDGES = 32768;

// pack 8 consecutive f32 -> 8 bf16 (rne) as uint4
__device__ inline uint4 cvt8(const float* __restrict__ p) {
    const float4* f = (const float4*)p;
    float4 a = f[0], b = f[1];
    union { uint4 u; bf16 h[8]; } pk;
    pk.h[0] = __float2bfloat16(a.x); pk.h[1] = __float2bfloat16(a.y);
    pk.h[2] = __float2bfloat16(a.z); pk.h[3] = __float2bfloat16(a.w);
    pk.h[4] = __float2bfloat16(b.x); pk.h[5] = __float2bfloat16(b.y);
    pk.h[6] = __float2bfloat16(b.z); pk.h[7] = __float2bfloat16(b.w);
    return pk.u;
}

// ---------------- generic BMxBN MFMA GEMM body (bf16 MFMA core) ------------
// Wave grid WM x WN (WM*WN*64 threads); wave tile (BM/WM)x(BN/WN).
// C[m,n] = epilogue( sum_k A[m,k] * B'[n,k] + bias[n] )
// AMODE 0: A bf16 scratch [M,K]
// AMODE 1: A f32 [M,K] (cvt in staging)
// AMODE 3: A row e = relu(U[sidx[e]][k] + V[ridx[e]][k]), U/V bf16 (K=512)
//          (b1 pre-folded into U by the UV GEMM's EPI 6)
// BMODE 1: B' row n = msg_W1[n&511][ (n>>9)*256 .. +K ]  (split W1 halves)
// BMODE 2: B' = Bt already bf16 [N,K] (pre-converted weights, no cvt)
// EPI 0: +bias, relu, store bf16 Cout[M,N]
// EPI 1: +bias, relu, atomicAdd fp32 into aggout[rIdx[row]*256+n]
// EPI 2: +bias, add f32 residual inputsF[m,n], store f32 OutF (N==256)
// EPI 6: +bias only where col<512 (b1 fold into U half), NO relu, bf16 store
template<int BM, int BN, int WM, int WN, int AMODE, int BMODE, int EPI>
__device__ __forceinline__ void gemm_body(
    const bf16* __restrict__ A, const float* __restrict__ Af,
    const float* __restrict__ Bt, const float* __restrict__ bias,
    bf16* __restrict__ Cout, float* __restrict__ OutF,
    const float* __restrict__ inputsF, const bf16* __restrict__ UVb,
    const int* __restrict__ sidx, const int* __restrict__ ridx,
    float* __restrict__ aggout, int M, int N, int K, int bx, int by)
{
    constexpr int BK = 32;
    constexpr int NT = WM * WN * 64;      // threads per block
    constexpr int RPP = NT / 4;           // staged rows per pass (32 elems/row)
    constexpr int PA = BM / RPP;          // A staging passes
    constexpr int PB = BN / RPP;
    constexpr int WTM = BM / WM;          // wave tile M
    constexpr int WTN = BN / WN;
    constexpr int MI = WTM / 16;
    constexpr int NJ = WTN / 16;
    __shared__ bf16 As[BM * BK];
    __shared__ bf16 Bs[BN * BK];
    __shared__ int sIdx[BM];
    __shared__ int rIdx[BM];

    const int t = threadIdx.x;
    const int m0 = by * BM;
    const int n0 = bx * BN;

    if constexpr (AMODE == 3) {
        if (t < BM) {
            sIdx[t] = sidx[m0 + t] & (NODES - 1);   // OOB structurally impossible
            rIdx[t] = ridx[m0 + t] & (NODES - 1);
        }
        __syncthreads();
    }

    // staging: thread t covers LDS row (p*RPP + t/4), 16B bf16 chunk (t%4)
    const int sr = t >> 2;
    const int sc = t & 3;

    uint4 ra[PA], rb[PB];

    auto loadTiles = [&](int kt) {
        const int kk = kt * BK + sc * 8;   // element column within K
#pragma unroll
        for (int p = 0; p < PA; ++p) {
            const int row = p * RPP + sr;
            if constexpr (AMODE == 0) {
                ra[p] = *(const uint4*)(A + (size_t)(m0 + row) * K + kk);
            } else if constexpr (AMODE == 1) {
                ra[p] = cvt8(Af + (size_t)(m0 + row) * K + kk);
            } else {
                union { uint4 q; unsigned short h[8]; } uu, vv;
                uu.q = *(const uint4*)(UVb + (size_t)sIdx[row] * 1024 + kk);
                vv.q = *(const uint4*)(UVb + (size_t)rIdx[row] * 1024 + 512 + kk);
                union { uint4 q; bf16 h[8]; } pk;
#pragma unroll
                for (int e = 0; e < 8; ++e) {
                    union { unsigned int u; float f; } a2, b2;
                    a2.u = (unsigned int)uu.h[e] << 16;
                    b2.u = (unsigned int)vv.h[e] << 16;
                    pk.h[e] = __float2bfloat16(fmaxf(a2.f + b2.f, 0.f));
                }
                ra[p] = pk.q;
            }
        }
#pragma unroll
        for (int p = 0; p < PB; ++p) {
            const int row = p * RPP + sr;
            if constexpr (BMODE == 2) {
                rb[p] = *(const uint4*)(((const bf16*)Bt) + (size_t)(n0 + row) * K + kk);
            } else {
                const int n = n0 + row;
                rb[p] = cvt8(Bt + (size_t)(n & 511) * 512 + (n >> 9) * 256 + kk);
            }
        }
    };

    const int wv = t >> 6;
    const int lane = t & 63;
    const int wm = wv / WN, wn = wv % WN;
    const int r16 = lane & 15, q = lane >> 4;

    floatx4 acc[MI][NJ] = {};

    loadTiles(0);
    const int KT = K / BK;
    for (int kt = 0; kt < KT; ++kt) {
        __syncthreads();
#pragma unroll
        for (int p = 0; p < PA; ++p)
            *(uint4*)(&As[(p * RPP + sr) * BK + sc * 8]) = ra[p];
#pragma unroll
        for (int p = 0; p < PB; ++p)
            *(uint4*)(&Bs[(p * RPP + sr) * BK + sc * 8]) = rb[p];
        __syncthreads();
        if (kt + 1 < KT) loadTiles(kt + 1);   // overlap next-tile loads with MFMA

        bf16x8 af[MI], bfr[NJ];
#pragma unroll
        for (int i = 0; i < MI; ++i)
            af[i] = *(const bf16x8*)(&As[(wm * WTM + i * 16 + r16) * BK + q * 8]);
#pragma unroll
        for (int j = 0; j < NJ; ++j)
            bfr[j] = *(const bf16x8*)(&Bs[(wn * WTN + j * 16 + r16) * BK + q * 8]);
#pragma unroll
        for (int i = 0; i < MI; ++i)
#pragma unroll
            for (int j = 0; j < NJ; ++j)
                acc[i][j] = __builtin_amdgcn_mfma_f32_16x16x32_bf16(af[i], bfr[j], acc[i][j], 0, 0, 0);
    }

    float bv[NJ];
#pragma unroll
    for (int j = 0; j < NJ; ++j) {
        const int gc = n0 + wn * WTN + j * 16 + r16;
        if constexpr (EPI == 6)
            bv[j] = (gc < 512) ? bias[gc] : 0.f;   // b1 fold: U half only
        else
            bv[j] = bias[gc];
    }

    // C/D layout: col = lane&15, row = q*4 + r (verified m89/m91)
#pragma unroll
    for (int i = 0; i < MI; ++i) {
        const int lr = wm * WTM + i * 16 + q * 4;
        const int rbase = m0 + lr;
#pragma unroll
        for (int j = 0; j < NJ; ++j) {
            const int gc = n0 + wn * WTN + j * 16 + r16;
#pragma unroll
            for (int r = 0; r < 4; ++r) {
                float v = acc[i][j][r] + bv[j];
                const int gr = rbase + r;
                if constexpr (EPI == 0) {
                    v = fmaxf(v, 0.0f);
                    Cout[(size_t)gr * N + gc] = __float2bfloat16(v);
                } else if constexpr (EPI == 1) {
                    v = fmaxf(v, 0.0f);
                    atomicAdd(&aggout[(size_t)rIdx[lr + r] * 256 + gc], v);
                } else if constexpr (EPI == 2) {
                    OutF[(size_t)gr * 256 + gc] = inputsF[(size_t)gr * 256 + gc] + v;
                } else {   // EPI 6
                    Cout[(size_t)gr * N + gc] = __float2bfloat16(v);
                }
            }
        }
    }
}

template<int BM, int BN, int WM, int WN, int AMODE, int BMODE, int EPI>
__global__ __launch_bounds__(WM * WN * 64, 2) void gemm_k(
    const bf16* __restrict__ A, const float* __restrict__ Af,
    const float* __restrict__ Bt, const float* __restrict__ bias,
    bf16* __restrict__ Cout, float* __restrict__ OutF,
    const float* __restrict__ inputsF, const bf16* __restrict__ UVb,
    const int* __restrict__ sidx, const int* __restrict__ ridx,
    float* __restrict__ aggout, int M, int N, int K)
{
    gemm_body<BM, BN, WM, WN, AMODE, BMODE, EPI>(A, Af, Bt, bias, Cout, OutF,
        inputsF, UVb, sidx, ridx, aggout, M, N, K, blockIdx.x, blockIdx.y);
}

// ---------------- fused node MLP: 3 layers pipelined per 16-row block ------
// Each block owns 16 nodes; layer outputs stay in LDS (bf16, padded stride
// 520 -> bank stride 4 dwords, max 2-way aliasing = free). B fragments are
// double-buffered in registers straight from the L2-resident bf16 weights.
template<int NJ, int EPI>   // EPI 0: relu -> LDS bf16 ; EPI 1: +inputs residual -> f32 global
__device__ __forceinline__ void mlp_layer(
    const bf16* __restrict__ Asrc, const bf16* __restrict__ W,
    const float* __restrict__ bias, bf16* __restrict__ dst,
    const float* __restrict__ inputsF, float* __restrict__ outF,
    int m0, int wv, int r16, int q)
{
    constexpr int LDR = 520;
    const int ncol0 = wv * NJ * 16;
    floatx4 acc[NJ] = {};
    bf16x8 bb0[NJ], bb1[NJ];
    bf16x8 aa0, aa1;

    auto loadB = [&](int kt, bf16x8* d) {
#pragma unroll
        for (int j = 0; j < NJ; ++j)
            d[j] = *(const bf16x8*)(W + (size_t)(ncol0 + j * 16 + r16) * 512 + kt * 32 + q * 8);
    };
    auto loadA = [&](int kt) {
        return *(const bf16x8*)(Asrc + r16 * LDR + kt * 32 + q * 8);
    };

    loadB(0, bb0); aa0 = loadA(0);
#pragma unroll
    for (int kt = 0; kt < 16; kt += 2) {
        loadB(kt + 1, bb1); aa1 = loadA(kt + 1);
#pragma unroll
        for (int j = 0; j < NJ; ++j)
            acc[j] = __builtin_amdgcn_mfma_f32_16x16x32_bf16(aa0, bb0[j], acc[j], 0, 0, 0);
        if (kt + 2 < 16) { loadB(kt + 2, bb0); aa0 = loadA(kt + 2); }
#pragma unroll
        for (int j = 0; j < NJ; ++j)
            acc[j] = __builtin_amdgcn_mfma_f32_16x16x32_bf16(aa1, bb1[j], acc[j], 0, 0, 0);
    }

    // C/D layout: col = lane&15, row = q*4 + r (verified m89/m91)
#pragma unroll
    for (int j = 0; j < NJ; ++j) {
        const int gc = ncol0 + j * 16 + r16;
        const float bvv = bias[gc];
#pragma unroll
        for (int r = 0; r < 4; ++r) {
            float v = acc[j][r] + bvv;
            const int lr = q * 4 + r;
            if constexpr (EPI == 0) {
                dst[lr * LDR + gc] = __float2bfloat16(fmaxf(v, 0.f));
            } else {
                const size_t o = (size_t)(m0 + lr) * 256 + gc;
                outF[o] = inputsF[o] + v;
            }
        }
    }
}

__global__ __launch_bounds__(256, 2) void node_mlp(
    const float* __restrict__ inputs, const float* __restrict__ agg,
    const bf16* __restrict__ W1b, const float* __restrict__ b1,
    const bf16* __restrict__ W2b, const float* __restrict__ b2,
    const bf16* __restrict__ W3b, const float* __restrict__ b3,
    float* __restrict__ out)
{
    constexpr int LDR = 520;
    __shared__ bf16 As[16 * LDR];
    __shared__ bf16 Hs[16 * LDR];
    __shared__ bf16 Gs[16 * LDR];
    const int t = threadIdx.x;
    const int m0 = blockIdx.x * 16;

    // stage A = concat(inputs, agg) rows m0..m0+15 as bf16 (coalesced 32B/lane)
#pragma unroll
    for (int p = 0; p < 4; ++p) {
        const int c = t + 256 * p;          // 1024 chunks of 8 elems
        const int row = c >> 6;
        const int col = (c & 63) * 8;
        const float* src = (col < 256)
            ? (inputs + (size_t)(m0 + row) * 256 + col)
            : (agg + (size_t)(m0 + row) * 256 + (col - 256));
        *(uint4*)(&As[row * LDR + col]) = cvt8(src);
    }
    const int wv = t >> 6, lane = t & 63;
    const int r16 = lane & 15, q = lane >> 4;
    __syncthreads();
    mlp_layer<8, 0>(As, W1b, b1, Hs, nullptr, nullptr, m0, wv, r16, q);
    __syncthreads();
    mlp_layer<8, 0>(Hs, W2b, b2, Gs, nullptr, nullptr, m0, wv, r16, q);
    __syncthreads();
    mlp_layer<4, 1>(Gs, W3b, b3, nullptr, inputs, out, m0, wv, r16, q);
}

// ---------------- fat front kernel: UV GEMM + zero + weight cvt + extract --
// blocks [0,512):      UV(bf16) = inputs @ [W1_left|W1_right]^T + [b1|0]
//                      (64x64 tiles, EPI 6 folds b1 into U half)
// blocks [512,1024):   zero agg (2 MB)
// blocks [1024,1408):  f32->bf16 weight conversion (msg_W2|out_W1|out_W2|out_W3)
// blocks [1408,17792): one-hot index extraction (one wave per row, early exit)
// __launch_bounds__(256,8): cap VGPR so the extract waves keep 8 waves/SIMD
// (extract is HBM-latency-bound, 1 load in flight/wave: occupancy IS bandwidth)
__global__ __launch_bounds__(256, 8) void fat_pre(
    const float* __restrict__ rel_rec, const float* __restrict__ rel_send,
    int* __restrict__ recv_idx, int* __restrict__ send_idx,
    float4* __restrict__ agg, const float* __restrict__ inputs,
    const float* __restrict__ msg_W1, const float* __restrict__ msg_b1,
    bf16* __restrict__ UVb,
    const float* __restrict__ msg_W2, const float* __restrict__ out_W1,
    const float* __restrict__ out_W2, const float* __restrict__ out_W3,
    bf16* __restrict__ Wc)
{
    const int b = blockIdx.x;
    if (b < 512) {
        gemm_body<64, 64, 2, 2, 1, 1, 6>(nullptr, inputs, msg_W1, msg_b1, UVb,
            nullptr, nullptr, nullptr, nullptr, nullptr, nullptr,
            NODES, 1024, 256, b & 15, b >> 4);
    } else if (b < 1024) {
        agg[(size_t)(b - 512) * 256 + threadIdx.x] = float4{0.f, 0.f, 0.f, 0.f};
    } else if (b < 1408) {
        // one-shot weight cvt: gid ranges are block-uniform (boundaries are
        // multiples of 2048), dst is contiguous [msgW2|outW1|outW2|outW3]
        const int gid = (b - 1024) * 2048 + threadIdx.x * 8;
        const float* src;
        if (gid < 131072)      src = msg_W2 + gid;
        else if (gid < 393216) src = out_W1 + (gid - 131072);
        else if (gid < 655360) src = out_W2 + (gid - 393216);
        else                   src = out_W3 + (gid - 655360);
        *(uint4*)(Wc + gid) = cvt8(src);
    } else {
        const int eb = b - 1408;
        const int half = eb >> 13;         // 0: rel_rec, 1: rel_send
        const int rb = eb & 8191;
        const float* mat = half ? rel_send : rel_rec;
        int* out = half ? send_idx : recv_idx;
        const int w = threadIdx.x >> 6;
        const int lane = threadIdx.x & 63;
        const int row = rb * 4 + w;        // 0..32767
        if (lane == 0) out[row] = 0;       // defensive init
        const uint4* base = (const uint4*)(mat + (size_t)row * NODES);
        for (int p = 0; p < 8; ++p) {
            uint4 v = base[p * 64 + lane];
            const bool hit = (v.x | v.y | v.z | v.w) != 0u;
            if (hit) {
                int e = v.x ? 0 : (v.y ? 1 : (v.z ? 2 : 3));
                out[row] = p * 256 + lane * 4 + e;
            }
            if (__any(hit)) break;         // wave early exit (avg ~4.5/8 passes)
        }
    }
}

extern "C" void kernel_launch(void* const* d_in, const int* in_sizes, int n_in,
                              void* d_out, int out_size, void* d_ws, size_t ws_size,
                              hipStream_t stream) {
    const float* inputs   = (const float*)d_in[0];
    const float* rel_rec  = (const float*)d_in[1];
    const float* rel_send = (const float*)d_in[2];
    const float* msg_W1   = (const float*)d_in[3];
    const float* msg_b1   = (const float*)d_in[4];
    const float* msg_W2   = (const float*)d_in[5];
    const float* msg_b2   = (const float*)d_in[6];
    const float* out_W1   = (const float*)d_in[7];
    const float* out_b1   = (const float*)d_in[8];
    const float* out_W2   = (const float*)d_in[9];
    const float* out_b2   = (const float*)d_in[10];
    const float* out_W3   = (const float*)d_in[11];
    const float* out_b3   = (const float*)d_in[12];

    // workspace layout (~8 MB used)
    char* ws = (char*)d_ws;
    int*   recv_idx = (int*)(ws + 0);            // 128 KB
    int*   send_idx = (int*)(ws + 131072);       // 128 KB
    float* agg      = (float*)(ws + 262144);     // 2 MB fp32 [2048,256]
    bf16*  UVb      = (bf16*)(ws + 2359296);     // 4 MB bf16 [2048,1024] (U|V)
    bf16*  Wc       = (bf16*)(ws + 6553600);     // 1.5 MB bf16 [msgW2|oW1|oW2|oW3]
    bf16*  W2b  = Wc;                            // 256x512
    bf16*  oW1b = Wc + 131072;                   // 512x512
    bf16*  oW2b = Wc + 393216;                   // 512x512
    bf16*  oW3b = Wc + 655360;                   // 256x512
    if (ws_size < (size_t)11 * 1024 * 1024) return;  // fail loudly, not fault

    // 1) fused: UV GEMM (first!) + agg zeroing + weight cvt + index extraction
    fat_pre<<<17792, 256, 0, stream>>>(rel_rec, rel_send, recv_idx, send_idx,
                                       (float4*)agg, inputs, msg_W1, msg_b1, UVb,
                                       msg_W2, out_W1, out_W2, out_W3, Wc);

    // 2) fused edge layer-2 + scatter, 128x256 tile, 512 threads, 256 blocks
    //    (= 1 block/CU): A gathered + repacked ONCE (vs twice at 128x128):
    //    agg[recv[e]] += relu( relu(U[send[e]]+V[recv[e]]) @ W2b^T + b2 )
    gemm_k<128, 256, 2, 4, 3, 2, 1><<<dim3(1, 256), 512, 0, stream>>>(
        nullptr, nullptr, (const float*)W2b, msg_b2, nullptr, nullptr,
        nullptr, UVb, send_idx, recv_idx, agg,
        EDGES, 256, 512);

    // 3) fused node MLP: out = inputs + mlp3(concat(inputs, agg))
    node_mlp<<<128, 256, 0, stream>>>(
        inputs, agg, oW1b, out_b1, oW2b, out_b2, oW3b, out_b3, (float*)d_out);
}